// Round 4
// baseline (183.593 us; speedup 1.0000x reference)
//
#include <hip/hip_runtime.h>

// Problem constants from the reference: x is (N, T, F) fp32.
constexpr int N_ = 64;
constexpr int T_ = 4096;
constexpr int F_ = 64;
constexpr int F4 = F_ / 4;            // 16 float4 per (n,t) row
constexpr int ROWS_PER_BLOCK = 64;    // 16 lanes/row, 4 rows per thread

// Reflect-pad + validity-mask gather.
//   src = rel<0 ? -rel : (rel<L ? rel : 2L-rel-2), clipped to [0, T-1]
//   out[n,t,:] = t < L+p0+p1 ? x[n,src,:] : 0
//
// v4: 16 lanes per row (one float4 each -> every load/store instruction
// covers 1 KB fully contiguous across the wave), and 4 rows per thread.
// Loads are UNCONDITIONAL (src is clamped to [0,T-1] so always in-bounds;
// invalid-tail rows read cache-resident rows) so the compiler issues 4
// independent global_load_dwordx4 back-to-back per lane -> 2x memory-level
// parallelism vs v3; validity is applied afterwards with a VALU select.
//
// NOTE (round 2 post-mortem): __builtin_nontemporal_store regressed 34 ->
// 59.5 us with WRITE_SIZE inflated 100 -> 153 MB: nt bypasses L2
// write-combining -> sub-line HBM writes + RMW. Dense streaming stores must
// go through L2 on gfx950.
__global__ __launch_bounds__(256) void pad_variable_kernel(
    const float4* __restrict__ x,
    const int*    __restrict__ lens,
    const int*    __restrict__ pad,   // (2, N) row-major: pad[0][n]=pad[n], pad[1][n]=pad[N_+n]
    float4*       __restrict__ out,
    int Tp)
{
    const int tid  = threadIdx.x;
    const int f4   = tid & (F4 - 1);      // float4 index within the row
    const int trow = tid >> 4;            // 0..15
    const int n    = blockIdx.y;          // wave-uniform -> lens/pad are s_loads

    const int L   = lens[n];
    const int p0  = pad[n];
    const int lim = L + p0 + pad[N_ + n]; // valid iff t < lim

    const int t0 = blockIdx.x * ROWS_PER_BLOCK + trow;

    const float4* __restrict__ xn = x   + (size_t)n * (T_ * F4) + f4;
    float4*       __restrict__ on = out + (size_t)n * Tp  * F4  + f4;

    int   t[4];
    float4 v[4];

    // Phase 1: 4 independent loads, no exec-mask churn.
    #pragma unroll
    for (int k = 0; k < 4; ++k) {
        t[k] = t0 + k * 16;
        const int rel = t[k] - p0;
        int src = (rel < 0) ? -rel : ((rel < L) ? rel : (2 * L - rel - 2));
        src = min(max(src, 0), T_ - 1);
        v[k] = xn[(size_t)src * F4];      // global_load_dwordx4, always safe
    }

    // Phase 2: validity select + stores (1 KB contiguous per instruction).
    const float4 zero = make_float4(0.f, 0.f, 0.f, 0.f);
    #pragma unroll
    for (int k = 0; k < 4; ++k) {
        if (t[k] < Tp) {
            on[(size_t)t[k] * F4] = (t[k] < lim) ? v[k] : zero;
        }
    }
}

extern "C" void kernel_launch(void* const* d_in, const int* in_sizes, int n_in,
                              void* d_out, int out_size, void* d_ws, size_t ws_size,
                              hipStream_t stream) {
    const float* x    = (const float*)d_in[0];
    const int*   lens = (const int*)d_in[1];
    const int*   pad  = (const int*)d_in[2];
    // d_in[3] is the Tp scalar on device; recover Tp from out_size instead
    // (out has N*Tp*F elements) so no device->host transfer is needed.
    const int Tp = out_size / (N_ * F_);

    dim3 block(256);
    dim3 grid((Tp + ROWS_PER_BLOCK - 1) / ROWS_PER_BLOCK, N_);
    hipLaunchKernelGGL(pad_variable_kernel, grid, block, 0, stream,
                       (const float4*)x, lens, pad, (float4*)d_out, Tp);
}

// Round 5
// 180.303 us; speedup vs baseline: 1.0182x; 1.0182x over previous
//
#include <hip/hip_runtime.h>

// Problem constants from the reference: x is (N, T, F) fp32.
constexpr int N_ = 64;
constexpr int T_ = 4096;
constexpr int F_ = 64;
constexpr int F4 = F_ / 4;                 // 16 float4 per (n,t) row
constexpr int ROWS_PER_PASS  = 16;         // 256 threads / 16 lanes-per-row
constexpr int PASSES         = 4;          // rows per thread
constexpr int ROWS_PER_BLOCK = ROWS_PER_PASS * PASSES;  // 64

// Reflect-pad + validity-mask gather.
//   src = rel<0 ? -rel : (rel<L ? rel : 2L-rel-2), clipped to [0, T-1]
//   out[n,t,:] = t < L+p0+p1 ? x[n,src,:] : 0
//
// v5: keep v4's 4-rows-per-thread batched-load structure (4 independent
// global_load_dwordx4 in flight per lane, scalar lens/pad amortized 4x),
// but fix v4's regression: invalid rows (t >= lim) no longer follow the
// reflected index (which walks real data rows backwards -> +47 MB FETCH +
// L2 thrash in v4). Instead their load index is cndmask'd to row 0 of the
// same n — one permanently L1/L2-hot 256 B line — and the result is
// selected to zero before the store. Loads stay unconditional (no
// exec-mask churn, full MLP); fetch returns to the compulsory ~34 MB.
//
// NOTE (round 2 post-mortem): __builtin_nontemporal_store regressed 34 ->
// 59.5 us with WRITE_SIZE inflated ~100 -> 153 MB: nt bypasses L2
// write-combining -> sub-line HBM writes + RMW. Dense streaming stores must
// go through L2 on gfx950.
__global__ __launch_bounds__(256) void pad_variable_kernel(
    const float4* __restrict__ x,
    const int*    __restrict__ lens,
    const int*    __restrict__ pad,   // (2, N) row-major: pad[0][n]=pad[n], pad[1][n]=pad[N_+n]
    float4*       __restrict__ out,
    int Tp)
{
    const int tid  = threadIdx.x;
    const int f4   = tid & (F4 - 1);      // float4 index within the row
    const int trow = tid >> 4;            // 0..15
    const int n    = blockIdx.y;          // wave-uniform -> lens/pad are s_loads

    const int L   = lens[n];
    const int p0  = pad[n];
    const int lim = L + p0 + pad[N_ + n]; // valid iff t < lim

    const int t0 = blockIdx.x * ROWS_PER_BLOCK + trow;

    const float4* __restrict__ xn = x   + (size_t)n * (T_ * F4) + f4;
    float4*       __restrict__ on = out + (size_t)n * Tp  * F4  + f4;

    int    t[PASSES];
    bool   valid[PASSES];
    float4 v[PASSES];

    // Phase 1: 4 independent loads, addresses fully resolved up front.
    #pragma unroll
    for (int k = 0; k < PASSES; ++k) {
        t[k] = t0 + k * ROWS_PER_PASS;
        const int rel = t[k] - p0;
        int src = (rel < 0) ? -rel : ((rel < L) ? rel : (2 * L - rel - 2));
        src = min(max(src, 0), T_ - 1);
        valid[k] = (t[k] < lim);
        src = valid[k] ? src : 0;         // invalid rows -> hot row 0, no extra fetch
        v[k] = xn[(size_t)src * F4];      // global_load_dwordx4, always in-bounds
    }

    // Phase 2: validity select + stores (1 KB contiguous per wave-instruction).
    const float4 zero = make_float4(0.f, 0.f, 0.f, 0.f);
    #pragma unroll
    for (int k = 0; k < PASSES; ++k) {
        if (t[k] < Tp) {
            on[(size_t)t[k] * F4] = valid[k] ? v[k] : zero;
        }
    }
}

extern "C" void kernel_launch(void* const* d_in, const int* in_sizes, int n_in,
                              void* d_out, int out_size, void* d_ws, size_t ws_size,
                              hipStream_t stream) {
    const float* x    = (const float*)d_in[0];
    const int*   lens = (const int*)d_in[1];
    const int*   pad  = (const int*)d_in[2];
    // d_in[3] is the Tp scalar on device; recover Tp from out_size instead
    // (out has N*Tp*F elements) so no device->host transfer is needed.
    const int Tp = out_size / (N_ * F_);

    dim3 block(256);
    dim3 grid((Tp + ROWS_PER_BLOCK - 1) / ROWS_PER_BLOCK, N_);
    hipLaunchKernelGGL(pad_variable_kernel, grid, block, 0, stream,
                       (const float4*)x, lens, pad, (float4*)d_out, Tp);
}

// Round 6
// 150.770 us; speedup vs baseline: 1.2177x; 1.1959x over previous
//
#include <hip/hip_runtime.h>

// Problem constants from the reference: x is (N, T, F) fp32.
constexpr int N_ = 64;
constexpr int T_ = 4096;
constexpr int F_ = 64;
constexpr int F4 = F_ / 4;   // 16 float4 per (n,t) row

// Reflect-pad + validity-mask gather.
//   src = rel<0 ? -rel : (rel<L ? rel : 2L-rel-2), clipped to [0, T-1]
//   out[n,t,:] = t < L+p0+p1 ? x[n,src,:] : 0
//
// v6 = R0 structure (best measured: 33.6 us) + XCD affinity by n.
//   - 16 threads (one float4 each) per (n,t) row -> 256 B contiguous
//     load+store per row; block of 256 covers 16 consecutive t rows.
//   - grid.x = n, grid.y = t-block. Linear wg id = n + tblock*64 and
//     64 % 8 == 0, so XCD = n % 8: ALL t-blocks of a given n share one
//     XCD's L2 (8 n's/XCD, ~1 MB x-rows + ~0.5 MB reflect-reuse each).
//     Previously adjacent t-blocks of one n round-robined across 8 XCDs,
//     duplicating reflected re-reads in every L2.
//
// Post-mortem ledger:
//   R2: nontemporal stores -> WRITE 153 MB (amplified), 60 us. nt bypasses
//       L2 write-combining; dense streaming stores must go through L2.
//   R4/R5: 4-rows/thread batched loads -> 70 us. 2x block footprint
//       thrashes L2 (FETCH 33 -> 70 MB = full x re-fetch). L2 residency
//       beats MLP for this gather; latency was never binding.
__global__ __launch_bounds__(256) void pad_variable_kernel(
    const float4* __restrict__ x,
    const int*    __restrict__ lens,
    const int*    __restrict__ pad,   // (2, N) row-major: pad[0][n]=pad[n], pad[1][n]=pad[N_+n]
    float4*       __restrict__ out,
    int Tp)
{
    const int tid  = threadIdx.x;
    const int f4   = tid & (F4 - 1);      // float4 index within F
    const int trow = tid >> 4;            // which of 16 t-rows this block handles
    const int n    = blockIdx.x;          // wave-uniform -> lens/pad become s_loads
    const int t    = blockIdx.y * 16 + trow;
    if (t >= Tp) return;

    const int L  = lens[n];
    const int p0 = pad[n];
    const int p1 = pad[N_ + n];

    const int rel = t - p0;
    int src = (rel < 0) ? -rel : ((rel < L) ? rel : (2 * L - rel - 2));
    src = min(max(src, 0), T_ - 1);

    const bool valid = t < (L + p0 + p1);

    float4 v = make_float4(0.f, 0.f, 0.f, 0.f);
    if (valid) {
        v = x[(size_t)n * T_ * F4 + (size_t)src * F4 + f4];
    }
    out[(size_t)n * Tp * F4 + (size_t)t * F4 + f4] = v;
}

extern "C" void kernel_launch(void* const* d_in, const int* in_sizes, int n_in,
                              void* d_out, int out_size, void* d_ws, size_t ws_size,
                              hipStream_t stream) {
    const float* x    = (const float*)d_in[0];
    const int*   lens = (const int*)d_in[1];
    const int*   pad  = (const int*)d_in[2];
    // d_in[3] is the Tp scalar on device; recover Tp from out_size instead
    // (out has N*Tp*F elements) so no device->host transfer is needed.
    const int Tp = out_size / (N_ * F_);

    dim3 block(256);
    dim3 grid(N_, (Tp + 15) / 16);        // x = n (XCD affinity), y = t-block
    hipLaunchKernelGGL(pad_variable_kernel, grid, block, 0, stream,
                       (const float4*)x, lens, pad, (float4*)d_out, Tp);
}

// Round 7
// 144.755 us; speedup vs baseline: 1.2683x; 1.0416x over previous
//
#include <hip/hip_runtime.h>

// Problem constants from the reference: x is (N, T, F) fp32.
constexpr int N_ = 64;
constexpr int T_ = 4096;
constexpr int F_ = 64;
constexpr int F4 = F_ / 4;   // 16 float4 per (n,t) row

// Reflect-pad + validity-mask gather.
//   src = rel<0 ? -rel : (rel<L ? rel : 2L-rel-2), clipped to [0, T-1]
//   out[n,t,:] = t < L+p0+p1 ? x[n,src,:] : 0
//
// FINAL = R0 structure (proven best: 33.6 us kernel slice, 145.2 us bench).
// 16 threads (one float4 each) per (n,t) row -> 256 B contiguous load+store
// per row; block of 256 covers 16 consecutive t rows; grid = (t-blocks, n).
// Natural dispatch order stripes consecutive t-blocks of one n across XCDs.
//
// Post-mortem ledger (kernel slice = bench - 111.6 us fixed poison fills):
//   R0  33.6 us  <- this structure. Best.
//   R3  35.7 us  8 lanes/row, 2 float4/lane: extra MLP neutral (latency not
//                binding; ~20 KB/CU in flight already supports >6 TB/s).
//   v6  38.9 us  n->XCD affinity: 8 n's x 1 MB reads through one 4 MB L2
//                thrashes; natural striped order is better.
//   R2  60.0 us  nontemporal stores: nt bypasses L2 write-combining ->
//                sub-line HBM writes, WRITE 100->153 MB.
//   R4  71.6 us  4 rows/thread: 2048 resident blocks x 32 KB footprint
//                = 64 MB >> 32 MB aggregate L2 -> full x re-fetch (FETCH
//                33->80 MB). L2 residency >> MLP for this gather.
// Remaining gap vs ~23 us clean floor is harness poison-flush pollution:
// two 370 MB pre-fills leave LLC dirty; our compulsory reads/writes force
// ~126 MB of in-window poison writebacks -> HBM-saturated during kernel.
__global__ __launch_bounds__(256) void pad_variable_kernel(
    const float4* __restrict__ x,
    const int*    __restrict__ lens,
    const int*    __restrict__ pad,   // (2, N) row-major: pad[0][n]=pad[n], pad[1][n]=pad[N_+n]
    float4*       __restrict__ out,
    int Tp)
{
    const int tid  = threadIdx.x;
    const int f4   = tid & (F4 - 1);      // float4 index within F
    const int trow = tid >> 4;            // which of 16 t-rows this block handles
    const int t    = blockIdx.x * 16 + trow;
    const int n    = blockIdx.y;          // wave-uniform -> lens/pad become s_loads
    if (t >= Tp) return;

    const int L  = lens[n];
    const int p0 = pad[n];
    const int p1 = pad[N_ + n];

    const int rel = t - p0;
    int src = (rel < 0) ? -rel : ((rel < L) ? rel : (2 * L - rel - 2));
    src = min(max(src, 0), T_ - 1);

    const bool valid = t < (L + p0 + p1);

    float4 v = make_float4(0.f, 0.f, 0.f, 0.f);
    if (valid) {
        v = x[(size_t)n * T_ * F4 + (size_t)src * F4 + f4];
    }
    out[(size_t)n * Tp * F4 + (size_t)t * F4 + f4] = v;
}

extern "C" void kernel_launch(void* const* d_in, const int* in_sizes, int n_in,
                              void* d_out, int out_size, void* d_ws, size_t ws_size,
                              hipStream_t stream) {
    const float* x    = (const float*)d_in[0];
    const int*   lens = (const int*)d_in[1];
    const int*   pad  = (const int*)d_in[2];
    // d_in[3] is the Tp scalar on device; recover Tp from out_size instead
    // (out has N*Tp*F elements) so no device->host transfer is needed.
    const int Tp = out_size / (N_ * F_);

    dim3 block(256);
    dim3 grid((Tp + 15) / 16, N_);
    hipLaunchKernelGGL(pad_variable_kernel, grid, block, 0, stream,
                       (const float4*)x, lens, pad, (float4*)d_out, Tp);
}